// Round 9
// baseline (452.301 us; speedup 1.0000x reference)
//
#include <hip/hip_runtime.h>
#include <hip/hip_bf16.h>

#define N_NODES 50000
#define N_EDGES 800000
#define NODE_F 128
#define EDGE_F 16
#define HID 64
#define N_ACT 6
#define NT_NODE (N_NODES / 16)   /* 3125 */
#define NT_EDGE (N_EDGES / 16)   /* 50000 */
#define NBKT 782                 /* ceil(50000/64) dst buckets (64 dsts each) */
#define NBLK_E 640               /* edge-slice blocks (cnt & bin) */
#define EPB (N_EDGES / NBLK_E)   /* 1250 edges per slice */
#define LCAP 1536                /* per-bucket LDS list capacity (mean 1024) */

typedef __bf16 bf16x8 __attribute__((ext_vector_type(8)));
typedef float f32x4 __attribute__((ext_vector_type(4)));

static __device__ __forceinline__ unsigned pk_bf16(float lo, float hi) {
    unsigned short a = __builtin_bit_cast(unsigned short, (__bf16)lo);
    unsigned short b = __builtin_bit_cast(unsigned short, (__bf16)hi);
    return (unsigned)a | ((unsigned)b << 16);
}
static __device__ __forceinline__ float blo(unsigned u) { return __uint_as_float(u << 16); }
static __device__ __forceinline__ float bhi(unsigned u) { return __uint_as_float(u & 0xffff0000u); }

#define CVT8(a, v0, v1) do { _Pragma("unroll") \
    for (int j = 0; j < 4; ++j) { a[j] = (__bf16)v0[j]; a[4 + j] = (__bf16)v1[j]; } } while (0)

// ================= Phase A: bucket-count || node GEMM || edge-head GEMM || edge-tail GEMM =================
#define A_CNT NBLK_E               /* 640 hist blocks */
#define A_NODE_HI (A_CNT + 330)    /* 970 */
#define A_HEAD_HI (A_NODE_HI + 45) /* 1015 */
#define A_GRID 1600                /* tail = 585 */
__launch_bounds__(256)
__global__ void k_pA(const int* __restrict__ ei, const float* __restrict__ x,
                     const float* __restrict__ ex, const float* __restrict__ Wn,
                     const float* __restrict__ We, const float* __restrict__ be,
                     int* __restrict__ counts, unsigned* __restrict__ hb,
                     float* __restrict__ poolS) {
    const int bid = blockIdx.x, tid = threadIdx.x;
    if (bid < A_CNT) {
        __shared__ int h[NBKT];
        for (int k = tid; k < NBKT; k += 256) h[k] = 0;
        __syncthreads();
        const int jend = (bid + 1) * EPB;
        for (int j = bid * EPB + tid; j < jend; j += 256)
            atomicAdd(&h[ei[N_EDGES + j] >> 6], 1);
        __syncthreads();
        for (int k = tid; k < NBKT; k += 256) counts[k * NBLK_E + bid] = h[k];
        return;
    }
    const int lane = tid & 63, wib = tid >> 6;
    const int g = lane >> 4, c = lane & 15;
    if (bid < A_NODE_HI) {
        // ---- node GEMM: hb[v] dwords 0..31 = bf16(node_x[v] @ Wn), UNSCALED ----
        bf16x8 bw[4][4];
#pragma unroll
        for (int s = 0; s < 4; ++s)
#pragma unroll
            for (int t = 0; t < 4; ++t) {
#pragma unroll
                for (int j = 0; j < 8; ++j)
                    bw[s][t][j] = (__bf16)Wn[(32 * s + 8 * g + j) * HID + t * 16 + c];
            }
        const int wv = (bid - A_CNT) * 4 + wib, nw = (A_NODE_HI - A_CNT) * 4;
        for (int tile = wv; tile < NT_NODE; tile += nw) {
            const int base = tile * 16;
            const float* p = x + (size_t)(base + c) * NODE_F + 8 * g;
            // issue all 8 loads first (MLP)
            f32x4 r0 = *(const f32x4*)(p);
            f32x4 r1 = *(const f32x4*)(p + 4);
            f32x4 r2 = *(const f32x4*)(p + 32);
            f32x4 r3 = *(const f32x4*)(p + 36);
            f32x4 r4 = *(const f32x4*)(p + 64);
            f32x4 r5 = *(const f32x4*)(p + 68);
            f32x4 r6 = *(const f32x4*)(p + 96);
            f32x4 r7 = *(const f32x4*)(p + 100);
            f32x4 acc0 = {}, acc1 = {}, acc2 = {}, acc3 = {};
            bf16x8 a;
            CVT8(a, r0, r1);
            acc0 = __builtin_amdgcn_mfma_f32_16x16x32_bf16(a, bw[0][0], acc0, 0, 0, 0);
            acc1 = __builtin_amdgcn_mfma_f32_16x16x32_bf16(a, bw[0][1], acc1, 0, 0, 0);
            acc2 = __builtin_amdgcn_mfma_f32_16x16x32_bf16(a, bw[0][2], acc2, 0, 0, 0);
            acc3 = __builtin_amdgcn_mfma_f32_16x16x32_bf16(a, bw[0][3], acc3, 0, 0, 0);
            CVT8(a, r2, r3);
            acc0 = __builtin_amdgcn_mfma_f32_16x16x32_bf16(a, bw[1][0], acc0, 0, 0, 0);
            acc1 = __builtin_amdgcn_mfma_f32_16x16x32_bf16(a, bw[1][1], acc1, 0, 0, 0);
            acc2 = __builtin_amdgcn_mfma_f32_16x16x32_bf16(a, bw[1][2], acc2, 0, 0, 0);
            acc3 = __builtin_amdgcn_mfma_f32_16x16x32_bf16(a, bw[1][3], acc3, 0, 0, 0);
            CVT8(a, r4, r5);
            acc0 = __builtin_amdgcn_mfma_f32_16x16x32_bf16(a, bw[2][0], acc0, 0, 0, 0);
            acc1 = __builtin_amdgcn_mfma_f32_16x16x32_bf16(a, bw[2][1], acc1, 0, 0, 0);
            acc2 = __builtin_amdgcn_mfma_f32_16x16x32_bf16(a, bw[2][2], acc2, 0, 0, 0);
            acc3 = __builtin_amdgcn_mfma_f32_16x16x32_bf16(a, bw[2][3], acc3, 0, 0, 0);
            CVT8(a, r6, r7);
            acc0 = __builtin_amdgcn_mfma_f32_16x16x32_bf16(a, bw[3][0], acc0, 0, 0, 0);
            acc1 = __builtin_amdgcn_mfma_f32_16x16x32_bf16(a, bw[3][1], acc1, 0, 0, 0);
            acc2 = __builtin_amdgcn_mfma_f32_16x16x32_bf16(a, bw[3][2], acc2, 0, 0, 0);
            acc3 = __builtin_amdgcn_mfma_f32_16x16x32_bf16(a, bw[3][3], acc3, 0, 0, 0);
#pragma unroll
            for (int q = 0; q < 4; ++q) {
                int i = base + 4 * g + q;
                hb[(size_t)i * 64 + c]      = pk_bf16(acc0[q], acc1[q]);
                hb[(size_t)i * 64 + 16 + c] = pk_bf16(acc2[q], acc3[q]);
            }
        }
        return;
    }
    bf16x8 bw[4];
#pragma unroll
    for (int t = 0; t < 4; ++t) {
        bw[t] = bf16x8{};
        if (g < 2) {
#pragma unroll
            for (int j = 0; j < 8; ++j)
                bw[t][j] = (__bf16)We[(8 * g + j) * HID + t * 16 + c];
        }
    }
    if (bid < A_HEAD_HI) {
        // ---- edge-head GEMM: rows < N_NODES -> hb dwords 32..63, 2-tile unrolled ----
        const int wv = (bid - A_NODE_HI) * 4 + wib, nw = (A_HEAD_HI - A_NODE_HI) * 4;
        int t0 = wv;
        for (; t0 + nw < NT_NODE; t0 += 2 * nw) {
            const int baseA = t0 * 16, baseB = (t0 + nw) * 16;
            bf16x8 aA{}, aB{};
            if (lane < 32) {
                const float* pA = ex + (size_t)(baseA + c) * EDGE_F + 8 * g;
                const float* pB = ex + (size_t)(baseB + c) * EDGE_F + 8 * g;
                f32x4 vA0 = *(const f32x4*)(pA);
                f32x4 vA1 = *(const f32x4*)(pA + 4);
                f32x4 vB0 = *(const f32x4*)(pB);
                f32x4 vB1 = *(const f32x4*)(pB + 4);
                CVT8(aA, vA0, vA1);
                CVT8(aB, vB0, vB1);
            }
            f32x4 A0 = {}, A1 = {}, A2 = {}, A3 = {};
            A0 = __builtin_amdgcn_mfma_f32_16x16x32_bf16(aA, bw[0], A0, 0, 0, 0);
            A1 = __builtin_amdgcn_mfma_f32_16x16x32_bf16(aA, bw[1], A1, 0, 0, 0);
            A2 = __builtin_amdgcn_mfma_f32_16x16x32_bf16(aA, bw[2], A2, 0, 0, 0);
            A3 = __builtin_amdgcn_mfma_f32_16x16x32_bf16(aA, bw[3], A3, 0, 0, 0);
            f32x4 B0 = {}, B1 = {}, B2 = {}, B3 = {};
            B0 = __builtin_amdgcn_mfma_f32_16x16x32_bf16(aB, bw[0], B0, 0, 0, 0);
            B1 = __builtin_amdgcn_mfma_f32_16x16x32_bf16(aB, bw[1], B1, 0, 0, 0);
            B2 = __builtin_amdgcn_mfma_f32_16x16x32_bf16(aB, bw[2], B2, 0, 0, 0);
            B3 = __builtin_amdgcn_mfma_f32_16x16x32_bf16(aB, bw[3], B3, 0, 0, 0);
#pragma unroll
            for (int q = 0; q < 4; ++q) {
                int iA = baseA + 4 * g + q, iB = baseB + 4 * g + q;
                hb[(size_t)iA * 64 + 32 + c] = pk_bf16(A0[q], A1[q]);
                hb[(size_t)iA * 64 + 48 + c] = pk_bf16(A2[q], A3[q]);
                hb[(size_t)iB * 64 + 32 + c] = pk_bf16(B0[q], B1[q]);
                hb[(size_t)iB * 64 + 48 + c] = pk_bf16(B2[q], B3[q]);
            }
        }
        if (t0 < NT_NODE) {
            const int base = t0 * 16;
            bf16x8 a{};
            if (lane < 32) {
                const float* p = ex + (size_t)(base + c) * EDGE_F + 8 * g;
                f32x4 v0 = *(const f32x4*)(p);
                f32x4 v1 = *(const f32x4*)(p + 4);
                CVT8(a, v0, v1);
            }
            f32x4 A0 = {}, A1 = {}, A2 = {}, A3 = {};
            A0 = __builtin_amdgcn_mfma_f32_16x16x32_bf16(a, bw[0], A0, 0, 0, 0);
            A1 = __builtin_amdgcn_mfma_f32_16x16x32_bf16(a, bw[1], A1, 0, 0, 0);
            A2 = __builtin_amdgcn_mfma_f32_16x16x32_bf16(a, bw[2], A2, 0, 0, 0);
            A3 = __builtin_amdgcn_mfma_f32_16x16x32_bf16(a, bw[3], A3, 0, 0, 0);
#pragma unroll
            for (int q = 0; q < 4; ++q) {
                int i = base + 4 * g + q;
                hb[(size_t)i * 64 + 32 + c] = pk_bf16(A0[q], A1[q]);
                hb[(size_t)i * 64 + 48 + c] = pk_bf16(A2[q], A3[q]);
            }
        }
        return;
    }
    // ---- edge-tail GEMM: rows >= N_NODES -> relu(h+be) to pool, 2-tile unrolled ----
    const float be0 = be[c], be1 = be[16 + c], be2 = be[32 + c], be3 = be[48 + c];
    float pe0 = 0.f, pe1 = 0.f, pe2 = 0.f, pe3 = 0.f;
    const int wv = (bid - A_HEAD_HI) * 4 + wib, nw = (A_GRID - A_HEAD_HI) * 4;
    int t0 = NT_NODE + wv;
    for (; t0 + nw < NT_EDGE; t0 += 2 * nw) {
        const int baseA = t0 * 16, baseB = (t0 + nw) * 16;
        bf16x8 aA{}, aB{};
        if (lane < 32) {
            const float* pA = ex + (size_t)(baseA + c) * EDGE_F + 8 * g;
            const float* pB = ex + (size_t)(baseB + c) * EDGE_F + 8 * g;
            f32x4 vA0 = *(const f32x4*)(pA);
            f32x4 vA1 = *(const f32x4*)(pA + 4);
            f32x4 vB0 = *(const f32x4*)(pB);
            f32x4 vB1 = *(const f32x4*)(pB + 4);
            CVT8(aA, vA0, vA1);
            CVT8(aB, vB0, vB1);
        }
        f32x4 A0 = {}, A1 = {}, A2 = {}, A3 = {};
        A0 = __builtin_amdgcn_mfma_f32_16x16x32_bf16(aA, bw[0], A0, 0, 0, 0);
        A1 = __builtin_amdgcn_mfma_f32_16x16x32_bf16(aA, bw[1], A1, 0, 0, 0);
        A2 = __builtin_amdgcn_mfma_f32_16x16x32_bf16(aA, bw[2], A2, 0, 0, 0);
        A3 = __builtin_amdgcn_mfma_f32_16x16x32_bf16(aA, bw[3], A3, 0, 0, 0);
        f32x4 B0 = {}, B1 = {}, B2 = {}, B3 = {};
        B0 = __builtin_amdgcn_mfma_f32_16x16x32_bf16(aB, bw[0], B0, 0, 0, 0);
        B1 = __builtin_amdgcn_mfma_f32_16x16x32_bf16(aB, bw[1], B1, 0, 0, 0);
        B2 = __builtin_amdgcn_mfma_f32_16x16x32_bf16(aB, bw[2], B2, 0, 0, 0);
        B3 = __builtin_amdgcn_mfma_f32_16x16x32_bf16(aB, bw[3], B3, 0, 0, 0);
#pragma unroll
        for (int q = 0; q < 4; ++q) {
            pe0 += fmaxf(A0[q] + be0, 0.f) + fmaxf(B0[q] + be0, 0.f);
            pe1 += fmaxf(A1[q] + be1, 0.f) + fmaxf(B1[q] + be1, 0.f);
            pe2 += fmaxf(A2[q] + be2, 0.f) + fmaxf(B2[q] + be2, 0.f);
            pe3 += fmaxf(A3[q] + be3, 0.f) + fmaxf(B3[q] + be3, 0.f);
        }
    }
    if (t0 < NT_EDGE) {
        const int base = t0 * 16;
        bf16x8 a{};
        if (lane < 32) {
            const float* p = ex + (size_t)(base + c) * EDGE_F + 8 * g;
            f32x4 v0 = *(const f32x4*)(p);
            f32x4 v1 = *(const f32x4*)(p + 4);
            CVT8(a, v0, v1);
        }
        f32x4 A0 = {}, A1 = {}, A2 = {}, A3 = {};
        A0 = __builtin_amdgcn_mfma_f32_16x16x32_bf16(a, bw[0], A0, 0, 0, 0);
        A1 = __builtin_amdgcn_mfma_f32_16x16x32_bf16(a, bw[1], A1, 0, 0, 0);
        A2 = __builtin_amdgcn_mfma_f32_16x16x32_bf16(a, bw[2], A2, 0, 0, 0);
        A3 = __builtin_amdgcn_mfma_f32_16x16x32_bf16(a, bw[3], A3, 0, 0, 0);
#pragma unroll
        for (int q = 0; q < 4; ++q) {
            pe0 += fmaxf(A0[q] + be0, 0.f);
            pe1 += fmaxf(A1[q] + be1, 0.f);
            pe2 += fmaxf(A2[q] + be2, 0.f);
            pe3 += fmaxf(A3[q] + be3, 0.f);
        }
    }
#pragma unroll
    for (int off = 16; off < 64; off <<= 1) {
        pe0 += __shfl_xor(pe0, off);
        pe1 += __shfl_xor(pe1, off);
        pe2 += __shfl_xor(pe2, off);
        pe3 += __shfl_xor(pe3, off);
    }
    if (g == 0) {
        float* sh = poolS + (bid & 7) * 128;
        atomicAdd(&sh[64 + 2 * c], pe0);
        atomicAdd(&sh[65 + 2 * c], pe1);
        atomicAdd(&sh[96 + 2 * c], pe2);
        atomicAdd(&sh[97 + 2 * c], pe3);
    }
}

// ================= scanB: per-bucket exclusive scan; LAST block computes gBases =================
__global__ void k_scanB(int* __restrict__ counts, int* __restrict__ totals,
                        int* __restrict__ gBases, int* __restrict__ doneS) {
    __shared__ int sd[NBLK_E];
    __shared__ int lastFlag;
    __shared__ int carrysh;
    const int k = blockIdx.x, t = threadIdx.x;
    const int v = counts[k * NBLK_E + t];
    sd[t] = v;
    __syncthreads();
    for (int o = 1; o < NBLK_E; o <<= 1) {
        int a = (t >= o) ? sd[t - o] : 0;
        __syncthreads();
        sd[t] += a;
        __syncthreads();
    }
    counts[k * NBLK_E + t] = sd[t] - v;   // exclusive within bucket
    if (t == NBLK_E - 1) totals[k] = sd[t];
    __threadfence();
    if (t == 0) lastFlag = (atomicAdd(doneS, 1) == NBKT - 1);
    __syncthreads();
    if (!lastFlag) return;
    __threadfence();
    // cross-bucket exclusive scan of totals -> gBases[0..NBKT]
    if (t == 0) carrysh = 0;
    __syncthreads();
#pragma unroll
    for (int ch = 0; ch < 2; ++ch) {          // 2*640 >= NBKT+1
        const int idx = ch * NBLK_E + t;
        const int vv = (idx < NBKT) ? totals[idx] : 0;
        const int carry = carrysh;
        sd[t] = vv;
        __syncthreads();
        for (int o = 1; o < NBLK_E; o <<= 1) {
            int a = (t >= o) ? sd[t - o] : 0;
            __syncthreads();
            sd[t] += a;
            __syncthreads();
        }
        if (idx <= NBKT) gBases[idx] = carry + sd[t] - vv;
        __syncthreads();
        if (t == NBLK_E - 1) carrysh = carry + sd[t];
        __syncthreads();
    }
}

// ================= bin: scatter packed edges to dst-bucketed regions (LDS cursors only) =================
__launch_bounds__(256)
__global__ void k_bin(const int* __restrict__ ei, const int* __restrict__ offs,
                      const int* __restrict__ gBases, unsigned* __restrict__ ebin) {
    __shared__ int cur[NBKT];
    const int bid = blockIdx.x, t = threadIdx.x;
    for (int k = t; k < NBKT; k += 256) cur[k] = gBases[k] + offs[k * NBLK_E + bid];
    __syncthreads();
    const int jend = (bid + 1) * EPB;
    for (int j = bid * EPB + t; j < jend; j += 256) {
        const int s = ei[j], d = ei[N_EDGES + j];
        const int pos = atomicAdd(&cur[d >> 6], 1);
        ebin[pos] = ((unsigned)(d & 63) << 16) | (unsigned)s;
    }
}

// ================= dinv + hb pre-scale (each block owns its bucket's 64 rows) =================
__launch_bounds__(256)
__global__ void k_dinvScale(const unsigned* __restrict__ ebin, const int* __restrict__ gBases,
                            float* __restrict__ dinv, unsigned* __restrict__ hb) {
    __shared__ int c[64];
    __shared__ float dvs[64];
    const int k = blockIdx.x, t = threadIdx.x;
    if (t < 64) c[t] = 0;
    __syncthreads();
    const int lo = gBases[k], hi = gBases[k + 1];
    for (int j = lo + t; j < hi; j += 256)
        atomicAdd(&c[(ebin[j] >> 16) & 63], 1);
    __syncthreads();
    if (t < 64) {
        const int v = k * 64 + t;
        if (v < N_NODES) {
            const float d = rsqrtf((float)c[t] + 1.0f);
            dinv[v] = d;
            dvs[t] = d;
        }
    }
    __syncthreads();
#pragma unroll
    for (int it = 0; it < 4; ++it) {
        const int chunk = t + 256 * it;
        const int r = chunk >> 4, q = chunk & 15;
        const int v = k * 64 + r;
        if (v < N_NODES) {
            const float d = dvs[r];
            unsigned* p = hb + (size_t)v * 64 + q * 4;
            uint4 u = *(uint4*)p;
            u.x = pk_bf16(d * blo(u.x), d * bhi(u.x));
            u.y = pk_bf16(d * blo(u.y), d * bhi(u.y));
            u.z = pk_bf16(d * blo(u.z), d * bhi(u.z));
            u.w = pk_bf16(d * blo(u.w), d * bhi(u.w));
            *(uint4*)p = u;
        }
    }
}

// ================= gather: CSR-in-LDS per bucket + convs + relu + pool; LAST block: FC+softmax =================
__launch_bounds__(512)
__global__ void k_gather(const unsigned* __restrict__ ebin, const int* __restrict__ gBases,
                         const float* __restrict__ dinv, const unsigned* __restrict__ hb,
                         const float* __restrict__ bn, const float* __restrict__ be,
                         float* __restrict__ poolS, const float* __restrict__ Wfc,
                         const float* __restrict__ bfc, float* __restrict__ out,
                         int* __restrict__ doneG) {
    __shared__ int cnts[64], off[64], cur[64];
    __shared__ unsigned short lists[LCAP];
    __shared__ float red[8][128];
    __shared__ int lastFlag;
    const int k = blockIdx.x, t = threadIdx.x;
    const int lane = t & 63, w = t >> 6;
    const int lo = gBases[k], ne = gBases[k + 1] - lo;
    if (t < 64) cnts[t] = 0;
    __syncthreads();
    for (int j = t; j < ne; j += 512)
        atomicAdd(&cnts[(ebin[lo + j] >> 16) & 63], 1);
    __syncthreads();
    if (t < 64) off[t] = cnts[t];
    __syncthreads();
    for (int o = 1; o < 64; o <<= 1) {
        int a = (t < 64 && t >= o) ? off[t - o] : 0;
        __syncthreads();
        if (t < 64) off[t] += a;
        __syncthreads();
    }
    if (t < 64) { const int ex = off[t] - cnts[t]; off[t] = ex; cur[t] = ex; }
    __syncthreads();
    for (int j = t; j < ne; j += 512) {
        const unsigned e = ebin[lo + j];
        const int pos = atomicAdd(&cur[(e >> 16) & 63], 1);
        if (pos < LCAP) lists[pos] = (unsigned short)(e & 0xFFFFu);
    }
    __syncthreads();

    const int p = lane & 31;
    const int col0 = (p < 16) ? p : p + 16;
    const float* bias = (lane < 32) ? bn : be;
    const float b0 = bias[col0], b1 = bias[col0 + 16];
    float p0 = 0.f, p1 = 0.f;
#pragma unroll
    for (int i = 0; i < 8; ++i) {
        const int dl = w + 8 * i;
        const int v = k * 64 + dl;
        if (v < N_NODES) {
            const float dv = dinv[v];
            const unsigned us = hb[(size_t)v * 64 + lane]; // self term (pre-scaled)
            float A0 = blo(us), A1 = bhi(us);
            float B0 = 0.f, B1 = 0.f, C0 = 0.f, C1 = 0.f, D0 = 0.f, D1 = 0.f;
            const int n = cnts[dl], b2 = off[dl];
            int kk = 0;
            for (; kk + 7 < n; kk += 8) {
                const int s0 = lists[b2 + kk],     s1 = lists[b2 + kk + 1];
                const int s2 = lists[b2 + kk + 2], s3 = lists[b2 + kk + 3];
                const int s4 = lists[b2 + kk + 4], s5 = lists[b2 + kk + 5];
                const int s6 = lists[b2 + kk + 6], s7 = lists[b2 + kk + 7];
                const unsigned u0 = hb[(size_t)s0 * 64 + lane];
                const unsigned u1 = hb[(size_t)s1 * 64 + lane];
                const unsigned u2 = hb[(size_t)s2 * 64 + lane];
                const unsigned u3 = hb[(size_t)s3 * 64 + lane];
                const unsigned u4 = hb[(size_t)s4 * 64 + lane];
                const unsigned u5 = hb[(size_t)s5 * 64 + lane];
                const unsigned u6 = hb[(size_t)s6 * 64 + lane];
                const unsigned u7 = hb[(size_t)s7 * 64 + lane];
                A0 += blo(u0); A1 += bhi(u0);
                B0 += blo(u1); B1 += bhi(u1);
                C0 += blo(u2); C1 += bhi(u2);
                D0 += blo(u3); D1 += bhi(u3);
                A0 += blo(u4); A1 += bhi(u4);
                B0 += blo(u5); B1 += bhi(u5);
                C0 += blo(u6); C1 += bhi(u6);
                D0 += blo(u7); D1 += bhi(u7);
            }
            for (; kk < n; ++kk) {
                const int s0 = lists[b2 + kk];
                const unsigned u0 = hb[(size_t)s0 * 64 + lane];
                A0 += blo(u0); A1 += bhi(u0);
            }
            const float S0 = (A0 + B0) + (C0 + D0);
            const float S1 = (A1 + B1) + (C1 + D1);
            p0 += fmaxf(fmaf(dv, S0, b0), 0.f);
            p1 += fmaxf(fmaf(dv, S1, b1), 0.f);
        }
    }
    red[w][2 * lane] = p0;
    red[w][2 * lane + 1] = p1;
    __syncthreads();
    if (w == 0) {
        float s0 = 0.f, s1 = 0.f;
#pragma unroll
        for (int r = 0; r < 8; ++r) { s0 += red[r][lane]; s1 += red[r][lane + 64]; }
        float* sh = poolS + (k & 7) * 128;
        atomicAdd(&sh[lane], s0);
        atomicAdd(&sh[lane + 64], s1);
    }
    // ---- last block: unpermute + means -> FC -> softmax ----
    __threadfence();
    if (t == 0) lastFlag = (atomicAdd(doneG, 1) == NBKT - 1);
    __syncthreads();
    if (!lastFlag) return;
    __threadfence();
    __shared__ float pool[128];
    __shared__ float logits[N_ACT];
    if (t < 128) {
        float s = 0.f;
        for (int sh = 0; sh < 8; ++sh) s += poolS[sh * 128 + t];
        const int half = t >> 6, r = t & 63, pp = r >> 1, slot = r & 1;
        const int col = ((pp < 16) ? pp : pp + 16) + 16 * slot + 64 * half;
        pool[col] = s * (half ? (1.0f / (float)N_EDGES) : (1.0f / (float)N_NODES));
    }
    __syncthreads();
    if (t < N_ACT) {
        float acc = bfc[t];
        for (int kk = 0; kk < 128; ++kk) acc = fmaf(pool[kk], Wfc[kk * N_ACT + t], acc);
        logits[t] = acc;
    }
    __syncthreads();
    if (t < N_ACT) {
        float m = logits[0];
        for (int a = 1; a < N_ACT; ++a) m = fmaxf(m, logits[a]);
        float sum = 0.f;
        for (int a = 0; a < N_ACT; ++a) sum += expf(logits[a] - m);
        out[t] = expf(logits[t] - m) / sum;
    }
}

extern "C" void kernel_launch(void* const* d_in, const int* in_sizes, int n_in,
                              void* d_out, int out_size, void* d_ws, size_t ws_size,
                              hipStream_t stream) {
    (void)in_sizes; (void)n_in; (void)out_size; (void)ws_size;
    const float* node_x = (const float*)d_in[0];
    const int*   ei     = (const int*)d_in[1];
    const float* edge_x = (const float*)d_in[2];
    const float* Wn     = (const float*)d_in[3];
    const float* bn     = (const float*)d_in[4];
    const float* We     = (const float*)d_in[5];
    const float* be     = (const float*)d_in[6];
    const float* Wfc    = (const float*)d_in[7];
    const float* bfc    = (const float*)d_in[8];
    float* out = (float*)d_out;

    // workspace layout (dwords)
    float*    ws     = (float*)d_ws;
    float*    poolS  = ws;                                    // 1024
    int*      doneS  = (int*)(ws + 1024);                     // 1
    int*      doneG  = (int*)(ws + 1025);                     // 1 (+pad to 1040)
    int*      counts = (int*)(ws + 1040);                     // NBKT*NBLK_E = 500480
    int*      totals = counts + NBKT * NBLK_E;                // 782 (+pad to 1024)
    int*      gBases = totals + 1024;                         // 783 (+pad to 1024)
    unsigned* ebin   = (unsigned*)(gBases + 1024);            // N_EDGES
    float*    dinv   = (float*)(ebin + N_EDGES);              // 50048
    unsigned* hb     = (unsigned*)(dinv + 50048);             // N_NODES * 64

    hipMemsetAsync(d_ws, 0, 1040 * 4, stream);                // pool shards + tickets

    k_pA       <<<A_GRID, 256, 0, stream>>>(ei, node_x, edge_x, Wn, We, be, counts, hb, poolS);
    k_scanB    <<<NBKT, NBLK_E, 0, stream>>>(counts, totals, gBases, doneS);
    k_bin      <<<NBLK_E, 256, 0, stream>>>(ei, counts, gBases, ebin);
    k_dinvScale<<<NBKT, 256, 0, stream>>>(ebin, gBases, dinv, hb);
    k_gather   <<<NBKT, 512, 0, stream>>>(ebin, gBases, dinv, hb, bn, be, poolS, Wfc, bfc, out, doneG);
}